// Round 1
// baseline (1186.468 us; speedup 1.0000x reference)
//
#include <hip/hip_runtime.h>
#include <hip/hip_bf16.h>

// DFFN fused implementation, fp32 vector ALU, bf16 intermediate.
// Pipeline: proj_in(1x1) -> per-channel 8x8 circular conv (== rfft2*filter*irfft2
// on the flat-reshaped "patches", which are 1x64 column runs) -> dw3x3 -> GELU gate
// -> proj_out(1x1).

#define BATCH 4
#define CIN   64
#define C2    256
#define HH    256
#define WW    256
#define HW    (HH*WW)

using bf16 = __hip_bfloat16;

__device__ __forceinline__ float bf2f(bf16 v){ return __bfloat162float(v); }
__device__ __forceinline__ bf16  f2bf(float v){ return __float2bfloat16(v); }

// ---------------------------------------------------------------------------
// K0: per-channel 8x8 circular-conv kernel from the rfft2 half-spectrum filter.
// K[m,n] = sum_v w_v * (ReG_v[m]*cos(v*n*pi/4) - ImG_v[m]*sin(v*n*pi/4))
// G_v[m] = (1/8) sum_u F[u,v] * e^{i*u*m*pi/4};  w_0=w_4=1/8, w_1..3=1/4.
// (All angles are multiples of pi/4 -> exact lookup tables, no trig error.)
// ---------------------------------------------------------------------------
__global__ void k_precompute(const float* __restrict__ F, float* __restrict__ Kc)
{
    const int c = threadIdx.x;                   // 256 threads = 256 channels
    const float R = 0.7071067811865476f;
    const float C8[8] = {1.f, R, 0.f, -R, -1.f, -R, 0.f, R};
    const float S8[8] = {0.f, R, 1.f, R, 0.f, -R, -1.f, -R};

    float Fv[8][5];
    for (int u = 0; u < 8; ++u)
        for (int v = 0; v < 5; ++v)
            Fv[u][v] = F[c*40 + u*5 + v];

    float ReG[5][8], ImG[5][8];
    for (int v = 0; v < 5; ++v)
        for (int m = 0; m < 8; ++m) {
            float re = 0.f, im = 0.f;
            for (int u = 0; u < 8; ++u) {
                int idx = (u*m) & 7;
                re += Fv[u][v] * C8[idx];
                im += Fv[u][v] * S8[idx];
            }
            ReG[v][m] = re * 0.125f;
            ImG[v][m] = im * 0.125f;
        }

    for (int m = 0; m < 8; ++m)
        for (int n = 0; n < 8; ++n) {
            float acc = 0.f;
            for (int v = 0; v < 5; ++v) {
                float wv = (v == 0 || v == 4) ? 0.125f : 0.25f;
                int idx = (v*n) & 7;
                acc += wv * (ReG[v][m]*C8[idx] - ImG[v][m]*S8[idx]);
            }
            Kc[c*64 + m*8 + n] = acc;
        }
}

// ---------------------------------------------------------------------------
// K1: per (b, h, 64-col run): proj_in GEMM (64ch -> 256ch) + circular 8x8 conv.
// LDS: xs = half x-tile (32ch x 64col), ysT[u][c2] stride 258 (conflict-free).
// Thread map GEMM: tid -> (cg=tid>>2 -> 4 out-ch, colg=tid&3 -> 16 cols).
// Thread map conv: tid = channel, 64 outputs in regs.
// Output s written as bf16 (halves HBM traffic; error budget analyzed OK).
// ---------------------------------------------------------------------------
__global__ __launch_bounds__(256, 2) void k1_proj_circ(
    const float* __restrict__ x, const float* __restrict__ w_in,
    const float* __restrict__ b_in, const float* __restrict__ Kc,
    bf16* __restrict__ s)
{
    __shared__ __align__(16) float xs[32*64];      // 8 KB
    __shared__ __align__(16) float ysT[64*258];    // 64.5 KB, [u][c2] stride 258

    const int tid = threadIdx.x;
    const int bid = blockIdx.x;
    const int run = bid & 3;
    const int h   = (bid >> 2) & 255;
    const int b   = bid >> 10;

    const int colg = tid & 3,  cg  = tid >> 2;
    const int col0 = colg * 16, c20 = cg * 4;

    float acc[4][16];
#pragma unroll
    for (int j = 0; j < 4; ++j) {
        float bv = b_in[c20 + j];
#pragma unroll
        for (int i = 0; i < 16; ++i) acc[j][i] = bv;
    }

    const float* xb = x + (long)b * CIN * HW + h * WW + run * 64;

    for (int half = 0; half < 2; ++half) {
        __syncthreads();   // xs reuse across halves
#pragma unroll
        for (int i = 0; i < 8; ++i) {
            int e = tid + i*256;
            int c = e >> 6, col = e & 63;
            xs[c*64 + col] = xb[(long)(half*32 + c) * HW + col];
        }
        __syncthreads();

        for (int c4 = 0; c4 < 32; c4 += 4) {
            float4 wv[4];
#pragma unroll
            for (int j = 0; j < 4; ++j)
                wv[j] = *(const float4*)&w_in[(c20 + j)*64 + half*32 + c4];
#pragma unroll
            for (int cc = 0; cc < 4; ++cc) {
                float4 xv[4];
#pragma unroll
                for (int k = 0; k < 4; ++k)
                    xv[k] = *(const float4*)&xs[(c4 + cc)*64 + col0 + 4*k];
#pragma unroll
                for (int j = 0; j < 4; ++j) {
                    float w = (cc == 0) ? wv[j].x : (cc == 1) ? wv[j].y
                             : (cc == 2) ? wv[j].z : wv[j].w;
#pragma unroll
                    for (int k = 0; k < 4; ++k) {
                        acc[j][4*k+0] += xv[k].x * w;
                        acc[j][4*k+1] += xv[k].y * w;
                        acc[j][4*k+2] += xv[k].z * w;
                        acc[j][4*k+3] += xv[k].w * w;
                    }
                }
            }
        }
    }

    // write y transposed: ysT[col][c2]
#pragma unroll
    for (int i = 0; i < 16; ++i) {
        float2 v0 = {acc[0][i], acc[1][i]};
        float2 v1 = {acc[2][i], acc[3][i]};
        *(float2*)&ysT[(col0 + i)*258 + c20]     = v0;
        *(float2*)&ysT[(col0 + i)*258 + c20 + 2] = v1;
    }
    __syncthreads();

    // circular conv: thread = channel tid
    const float* Kp = Kc + tid*64;
    float o[64];
#pragma unroll
    for (int i = 0; i < 64; ++i) o[i] = 0.f;

#pragma unroll
    for (int a = 0; a < 8; ++a) {
        for (int m = 0; m < 8; ++m) {
            int r = (a - m) & 7;
            float yy[8];
#pragma unroll
            for (int q = 0; q < 8; ++q) yy[q] = ysT[(r*8 + q)*258 + tid];
#pragma unroll
            for (int n = 0; n < 8; ++n) {
                float kk = Kp[m*8 + n];
#pragma unroll
                for (int bb = 0; bb < 8; ++bb)
                    o[a*8 + bb] += kk * yy[(bb - n) & 7];
            }
        }
    }

    // write back into own column (only this thread touches column tid)
#pragma unroll
    for (int u = 0; u < 64; ++u) ysT[u*258 + tid] = o[u];
    __syncthreads();

    // cooperative coalesced bf16 store
    bf16* sp = s + (long)b * C2 * HW + h * WW + run * 64;
#pragma unroll
    for (int i = 0; i < 64; ++i) {
        int e = tid + i*256;
        int c2e = e >> 6, u = e & 63;
        sp[(long)c2e * HW + u] = f2bf(ysT[u*258 + c2e]);
    }
}

// ---------------------------------------------------------------------------
// K2: per (b, h, run): dw3x3 + bias -> GELU gate -> proj_out (128->64).
// XCD-aware swizzle: h-adjacent blocks land on the same XCD so the 3-row s
// halo is served by that XCD's L2.
// ---------------------------------------------------------------------------
__global__ __launch_bounds__(256, 2) void k2_dw_gelu_out(
    const bf16* __restrict__ s, const float* __restrict__ w_dw,
    const float* __restrict__ b_dw, const float* __restrict__ w_out,
    const float* __restrict__ b_out, float* __restrict__ out)
{
    __shared__ float tb[C2*64];   // 64 KB: t then (in-place, c<128) g

    const int tid = threadIdx.x;
    const int l   = ((blockIdx.x & 7) << 9) | (blockIdx.x >> 3);  // XCD swizzle
    const int run = l & 3;
    const int h   = (l >> 2) & 255;
    const int b   = l >> 10;
    const int col = tid & 63, rg = tid >> 6;
    const int wc  = run*64 + col;

    // depthwise 3x3 (SAME, zero pad) for channels rg*64 .. rg*64+63
    for (int k = 0; k < 64; ++k) {
        int c2 = __builtin_amdgcn_readfirstlane(rg*64 + k);   // wave-uniform
        float a = b_dw[c2];
        const bf16* spc = s + ((long)b * C2 + c2) * HW;
#pragma unroll
        for (int dy = 0; dy < 3; ++dy) {
            int hy = h + dy - 1;
            if (hy < 0 || hy >= HH) continue;
            const bf16* rp = spc + hy*WW;
#pragma unroll
            for (int dx = 0; dx < 3; ++dx) {
                int wx = wc + dx - 1;
                if (wx >= 0 && wx < WW)
                    a += bf2f(rp[wx]) * w_dw[c2*9 + dy*3 + dx];
            }
        }
        tb[(rg*64 + k)*64 + col] = a;
    }
    __syncthreads();

    // GELU(x1) * x2, exact erf; in-place into tb[c] for c<128
#pragma unroll
    for (int i = 0; i < 32; ++i) {
        int c = rg + 4*i;                       // 0..127, each (c,col) once
        float t1 = tb[c*64 + col];
        float t2 = tb[(c + 128)*64 + col];
        float g = t1 * 0.5f * (1.0f + erff(t1 * 0.7071067811865476f)) * t2;
        tb[c*64 + col] = g;
    }
    __syncthreads();

    // proj_out: wave rg handles out channels rg*16 .. rg*16+15
    const int og = __builtin_amdgcn_readfirstlane(rg);
    float acc[16];
#pragma unroll
    for (int i = 0; i < 16; ++i) acc[i] = b_out[og*16 + i];
    for (int c = 0; c < 128; c += 4) {
        float g0 = tb[(c+0)*64 + col];
        float g1 = tb[(c+1)*64 + col];
        float g2 = tb[(c+2)*64 + col];
        float g3 = tb[(c+3)*64 + col];
#pragma unroll
        for (int i = 0; i < 16; ++i) {
            const float4 wv = *(const float4*)&w_out[(og*16 + i)*128 + c];
            acc[i] += g0*wv.x + g1*wv.y + g2*wv.z + g3*wv.w;
        }
    }
    float* op = out + (long)b * CIN * HW + h * WW + wc;
#pragma unroll
    for (int i = 0; i < 16; ++i)
        op[(long)(og*16 + i) * HW] = acc[i];
}

// ---------------------------------------------------------------------------
extern "C" void kernel_launch(void* const* d_in, const int* in_sizes, int n_in,
                              void* d_out, int out_size, void* d_ws, size_t ws_size,
                              hipStream_t stream) {
    const float* x     = (const float*)d_in[0];
    const float* w_in  = (const float*)d_in[1];
    const float* b_in  = (const float*)d_in[2];
    const float* ff    = (const float*)d_in[3];
    const float* w_dw  = (const float*)d_in[4];
    const float* b_dw  = (const float*)d_in[5];
    const float* w_out = (const float*)d_in[6];
    const float* b_out = (const float*)d_in[7];
    float* out = (float*)d_out;

    float* Kc = (float*)d_ws;                           // 64 KB
    bf16*  s  = (bf16*)((char*)d_ws + 65536);           // 128 MB intermediate

    hipLaunchKernelGGL(k_precompute,   dim3(1),    dim3(256), 0, stream, ff, Kc);
    hipLaunchKernelGGL(k1_proj_circ,   dim3(4096), dim3(256), 0, stream,
                       x, w_in, b_in, Kc, s);
    hipLaunchKernelGGL(k2_dw_gelu_out, dim3(4096), dim3(256), 0, stream,
                       s, w_dw, b_dw, w_out, b_out, out);
}

// Round 2
// 633.885 us; speedup vs baseline: 1.8717x; 1.8717x over previous
//
#include <hip/hip_runtime.h>
#include <hip/hip_bf16.h>

// DFFN fused implementation, fp32 vector ALU, bf16 channels-LAST intermediate.
// Pipeline: proj_in(1x1) -> per-channel 8x8 circular conv (== rfft2*filter*irfft2
// on the flat-reshaped "patches" = 1x64 column runs) -> dw3x3 -> GELU gate
// -> proj_out(1x1).
// R1 change: s layout [b][h][w][c2] (channels-last) so k2's dw-conv reads are
// per-thread dwordx4 of 8 contiguous channels (72 independent 16B loads/thread)
// instead of 576 scalar bf16 loads; k2 LDS 64->33 KB (2->4 blocks/CU).

#define BATCH 4
#define CIN   64
#define C2    256
#define HH    256
#define WW    256
#define HW    (HH*WW)

using bf16 = __hip_bfloat16;

__device__ __forceinline__ float bf2f(bf16 v){ return __bfloat162float(v); }
__device__ __forceinline__ bf16  f2bf(float v){ return __float2bfloat16(v); }

__device__ __forceinline__ void unpack8(uint4 v, float* f) {
    unsigned a0 = v.x, a1 = v.y, a2 = v.z, a3 = v.w;
    f[0] = __uint_as_float(a0 << 16); f[1] = __uint_as_float(a0 & 0xffff0000u);
    f[2] = __uint_as_float(a1 << 16); f[3] = __uint_as_float(a1 & 0xffff0000u);
    f[4] = __uint_as_float(a2 << 16); f[5] = __uint_as_float(a2 & 0xffff0000u);
    f[6] = __uint_as_float(a3 << 16); f[7] = __uint_as_float(a3 & 0xffff0000u);
}

// ---------------------------------------------------------------------------
// K0: per-channel 8x8 circular-conv kernel from the rfft2 half-spectrum filter.
// K[m,n] = sum_v w_v * (ReG_v[m]*cos(v*n*pi/4) - ImG_v[m]*sin(v*n*pi/4))
// G_v[m] = (1/8) sum_u F[u,v] * e^{i*u*m*pi/4};  w_0=w_4=1/8, w_1..3=1/4.
// ---------------------------------------------------------------------------
__global__ void k_precompute(const float* __restrict__ F, float* __restrict__ Kc)
{
    const int c = threadIdx.x;                   // 256 threads = 256 channels
    const float R = 0.7071067811865476f;
    const float C8[8] = {1.f, R, 0.f, -R, -1.f, -R, 0.f, R};
    const float S8[8] = {0.f, R, 1.f, R, 0.f, -R, -1.f, -R};

    float Fv[8][5];
    for (int u = 0; u < 8; ++u)
        for (int v = 0; v < 5; ++v)
            Fv[u][v] = F[c*40 + u*5 + v];

    float ReG[5][8], ImG[5][8];
    for (int v = 0; v < 5; ++v)
        for (int m = 0; m < 8; ++m) {
            float re = 0.f, im = 0.f;
            for (int u = 0; u < 8; ++u) {
                int idx = (u*m) & 7;
                re += Fv[u][v] * C8[idx];
                im += Fv[u][v] * S8[idx];
            }
            ReG[v][m] = re * 0.125f;
            ImG[v][m] = im * 0.125f;
        }

    for (int m = 0; m < 8; ++m)
        for (int n = 0; n < 8; ++n) {
            float acc = 0.f;
            for (int v = 0; v < 5; ++v) {
                float wv = (v == 0 || v == 4) ? 0.125f : 0.25f;
                int idx = (v*n) & 7;
                acc += wv * (ReG[v][m]*C8[idx] - ImG[v][m]*S8[idx]);
            }
            Kc[c*64 + m*8 + n] = acc;
        }
}

// ---------------------------------------------------------------------------
// K1: per (b, h, 64-col run): proj_in GEMM (64ch -> 256ch) + circular 8x8 conv.
// Output s written channels-last: s[((b*HH+h)*WW + w)*C2 + c], bf16.
// ---------------------------------------------------------------------------
__global__ __launch_bounds__(256, 2) void k1_proj_circ(
    const float* __restrict__ x, const float* __restrict__ w_in,
    const float* __restrict__ b_in, const float* __restrict__ Kc,
    bf16* __restrict__ s)
{
    __shared__ __align__(16) float xs[32*64];      // 8 KB
    __shared__ __align__(16) float ysT[64*258];    // 64.5 KB, [u][c2] stride 258

    const int tid = threadIdx.x;
    const int bid = blockIdx.x;
    const int run = bid & 3;
    const int h   = (bid >> 2) & 255;
    const int b   = bid >> 10;

    const int colg = tid & 3,  cg  = tid >> 2;
    const int col0 = colg * 16, c20 = cg * 4;

    float acc[4][16];
#pragma unroll
    for (int j = 0; j < 4; ++j) {
        float bv = b_in[c20 + j];
#pragma unroll
        for (int i = 0; i < 16; ++i) acc[j][i] = bv;
    }

    const float* xb = x + (long)b * CIN * HW + h * WW + run * 64;

    for (int half = 0; half < 2; ++half) {
        __syncthreads();   // xs reuse across halves
#pragma unroll
        for (int i = 0; i < 8; ++i) {
            int e = tid + i*256;
            int c = e >> 6, col = e & 63;
            xs[c*64 + col] = xb[(long)(half*32 + c) * HW + col];
        }
        __syncthreads();

        for (int c4 = 0; c4 < 32; c4 += 4) {
            float4 wv[4];
#pragma unroll
            for (int j = 0; j < 4; ++j)
                wv[j] = *(const float4*)&w_in[(c20 + j)*64 + half*32 + c4];
#pragma unroll
            for (int cc = 0; cc < 4; ++cc) {
                float4 xv[4];
#pragma unroll
                for (int k = 0; k < 4; ++k)
                    xv[k] = *(const float4*)&xs[(c4 + cc)*64 + col0 + 4*k];
#pragma unroll
                for (int j = 0; j < 4; ++j) {
                    float w = (cc == 0) ? wv[j].x : (cc == 1) ? wv[j].y
                             : (cc == 2) ? wv[j].z : wv[j].w;
#pragma unroll
                    for (int k = 0; k < 4; ++k) {
                        acc[j][4*k+0] += xv[k].x * w;
                        acc[j][4*k+1] += xv[k].y * w;
                        acc[j][4*k+2] += xv[k].z * w;
                        acc[j][4*k+3] += xv[k].w * w;
                    }
                }
            }
        }
    }

    // write y transposed: ysT[col][c2]
#pragma unroll
    for (int i = 0; i < 16; ++i) {
        float2 v0 = {acc[0][i], acc[1][i]};
        float2 v1 = {acc[2][i], acc[3][i]};
        *(float2*)&ysT[(col0 + i)*258 + c20]     = v0;
        *(float2*)&ysT[(col0 + i)*258 + c20 + 2] = v1;
    }
    __syncthreads();

    // circular conv: thread = channel tid
    const float* Kp = Kc + tid*64;
    float o[64];
#pragma unroll
    for (int i = 0; i < 64; ++i) o[i] = 0.f;

#pragma unroll
    for (int a = 0; a < 8; ++a) {
        for (int m = 0; m < 8; ++m) {
            int r = (a - m) & 7;
            float yy[8];
#pragma unroll
            for (int q = 0; q < 8; ++q) yy[q] = ysT[(r*8 + q)*258 + tid];
#pragma unroll
            for (int n = 0; n < 8; ++n) {
                float kk = Kp[m*8 + n];
#pragma unroll
                for (int bb = 0; bb < 8; ++bb)
                    o[a*8 + bb] += kk * yy[(bb - n) & 7];
            }
        }
    }

    // write back into own column (only this thread touches column tid)
#pragma unroll
    for (int u = 0; u < 64; ++u) ysT[u*258 + tid] = o[u];
    __syncthreads();

    // channels-last coalesced bf16 store: s[((b*HH+h)*WW + run*64+u)*C2 + c]
    bf16* sp = s + (((long)(b * HH + h) * WW) + run * 64) * C2;
    const int uo = tid >> 5;          // 0..7
    const int c0 = (tid & 31) * 8;    // 0..248
#pragma unroll
    for (int pass = 0; pass < 8; ++pass) {
        int u = pass * 8 + uo;
        unsigned r[4];
#pragma unroll
        for (int k = 0; k < 4; ++k) {
            unsigned lo = __float_as_uint(ysT[u*258 + c0 + 2*k    ]);
            unsigned hi = __float_as_uint(ysT[u*258 + c0 + 2*k + 1]);
            // round-to-nearest-even bf16 pack
            lo = (lo + 0x7fff + ((lo >> 16) & 1)) >> 16;
            hi = (hi + 0x7fff + ((hi >> 16) & 1)) & 0xffff0000u;
            r[k] = lo | hi;
        }
        *(uint4*)(sp + (long)u * C2 + c0) = make_uint4(r[0], r[1], r[2], r[3]);
    }
}

// ---------------------------------------------------------------------------
// K2: per (b, h, run of 64 px): dw3x3 + bias -> GELU gate -> proj_out (128->64).
// s is channels-last. Phase 1: thread = (px=lane, chunk-pair of 8 ch), 4 tasks;
// 18 x 16B global loads per task. g stored transposed in LDS [c][px] stride 65.
// Phase 2: wave rg -> out channels rg*16..+15, lane = px.
// ---------------------------------------------------------------------------
__global__ __launch_bounds__(256, 4) void k2_dw_gelu_out(
    const bf16* __restrict__ s, const float* __restrict__ w_dw,
    const float* __restrict__ b_dw, const float* __restrict__ w_out,
    const float* __restrict__ b_out, float* __restrict__ out)
{
    __shared__ float tb[128*65];   // 33.3 KB: g[c][px], stride 65

    const int tid = threadIdx.x;
    const int l   = ((blockIdx.x & 7) << 9) | (blockIdx.x >> 3);  // XCD swizzle
    const int run = l & 3;
    const int h   = (l >> 2) & 255;
    const int b   = l >> 10;
    const int wl  = tid & 63, rg = tid >> 6;
    const int w   = run*64 + wl;

#pragma unroll
    for (int i = 0; i < 4; ++i) {
        const int c0 = __builtin_amdgcn_readfirstlane((rg + 4*i) * 8); // 0..120, uniform
        float t1[8], t2[8];
#pragma unroll
        for (int j = 0; j < 8; ++j) { t1[j] = b_dw[c0+j]; t2[j] = b_dw[c0+128+j]; }

#pragma unroll
        for (int dy = 0; dy < 3; ++dy) {
            const int hy = h + dy - 1;
            if ((unsigned)hy >= HH) continue;          // wave-uniform
#pragma unroll
            for (int dx = 0; dx < 3; ++dx) {
                const int wx = w + dx - 1;
                if ((unsigned)wx < WW) {               // diverges only at image edge
                    const bf16* p = s + (((long)(b*HH + hy)*WW + wx) * C2 + c0);
                    uint4 v1 = *(const uint4*)p;
                    uint4 v2 = *(const uint4*)(p + 128);
                    float f1[8], f2[8];
                    unpack8(v1, f1); unpack8(v2, f2);
#pragma unroll
                    for (int j = 0; j < 8; ++j) {
                        t1[j] += f1[j] * w_dw[(c0+j)*9       + dy*3 + dx];
                        t2[j] += f2[j] * w_dw[(c0+128+j)*9   + dy*3 + dx];
                    }
                }
            }
        }
        // GELU(t1)*t2, exact erf; store transposed
#pragma unroll
        for (int j = 0; j < 8; ++j) {
            float g = t1[j] * 0.5f * (1.0f + erff(t1[j] * 0.7071067811865476f)) * t2[j];
            tb[(c0 + j)*65 + wl] = g;
        }
    }
    __syncthreads();

    // proj_out: wave rg handles out channels rg*16 .. rg*16+15, lane = px
    const int og = __builtin_amdgcn_readfirstlane(rg);
    float acc[16];
#pragma unroll
    for (int i = 0; i < 16; ++i) acc[i] = b_out[og*16 + i];
    for (int c = 0; c < 128; c += 4) {
        float g0 = tb[(c+0)*65 + wl];
        float g1 = tb[(c+1)*65 + wl];
        float g2 = tb[(c+2)*65 + wl];
        float g3 = tb[(c+3)*65 + wl];
#pragma unroll
        for (int i = 0; i < 16; ++i) {
            const float4 wv = *(const float4*)&w_out[(og*16 + i)*128 + c];
            acc[i] += g0*wv.x + g1*wv.y + g2*wv.z + g3*wv.w;
        }
    }
    float* op = out + (long)b * CIN * HW + h * WW + w;
#pragma unroll
    for (int i = 0; i < 16; ++i)
        op[(long)(og*16 + i) * HW] = acc[i];
}

// ---------------------------------------------------------------------------
extern "C" void kernel_launch(void* const* d_in, const int* in_sizes, int n_in,
                              void* d_out, int out_size, void* d_ws, size_t ws_size,
                              hipStream_t stream) {
    const float* x     = (const float*)d_in[0];
    const float* w_in  = (const float*)d_in[1];
    const float* b_in  = (const float*)d_in[2];
    const float* ff    = (const float*)d_in[3];
    const float* w_dw  = (const float*)d_in[4];
    const float* b_dw  = (const float*)d_in[5];
    const float* w_out = (const float*)d_in[6];
    const float* b_out = (const float*)d_in[7];
    float* out = (float*)d_out;

    float* Kc = (float*)d_ws;                           // 64 KB
    bf16*  s  = (bf16*)((char*)d_ws + 65536);           // 128 MB intermediate

    hipLaunchKernelGGL(k_precompute,   dim3(1),    dim3(256), 0, stream, ff, Kc);
    hipLaunchKernelGGL(k1_proj_circ,   dim3(4096), dim3(256), 0, stream,
                       x, w_in, b_in, Kc, s);
    hipLaunchKernelGGL(k2_dw_gelu_out, dim3(4096), dim3(256), 0, stream,
                       s, w_dw, b_dw, w_out, b_out, out);
}